// Round 11
// baseline (47.696 us; speedup 1.0000x reference)
//
#include <hip/hip_runtime.h>
#include <math.h>

#define CHUNK 32
#define NPOS 60
#define TWO_PI_F 6.283185307179586f
#define INV_TWO_PI_F 0.15915494309189535f
#define PI_F 3.14159265358979f

__device__ __forceinline__ float bcastf(float v, int l) {
    return __builtin_bit_cast(float, __builtin_amdgcn_readlane(__builtin_bit_cast(int, v), l));
}

// acos via Abramowitz-Stegun 4-term: max abs err ~6.7e-5 rad
__device__ __forceinline__ float acos_poly(float x) {
    const float ax = fabsf(x);
    const float s = __builtin_amdgcn_sqrtf(fmaxf(0.0f, 1.0f - ax));
    float p = fmaf(ax, -0.0187293f, 0.0742610f);
    p = fmaf(ax, p, -0.2121144f);
    p = fmaf(ax, p, 1.5707288f);
    const float r = s * p;
    return (x < 0.0f) ? (PI_F - r) : r;
}

__device__ __forceinline__ void hw_sincos_rev(float rev, float* s, float* c) {
    const float f = __builtin_amdgcn_fractf(rev);
    *s = __builtin_amdgcn_sinf(f);
    *c = __builtin_amdgcn_cosf(f);
}

// One row's contribution. FULLY BRANCHLESS (branches in the unrolled body
// collapse the burst pipeline -- R7/R9). Per-row consts via readlane (SGPR).
__device__ __forceinline__ void row_acc(
    int rr, float txj, float tyj, float flane, bool inpos,
    float th2min_rev, float stp_rev, float ca5, float sa5,
    float P, float Q, float R, float S, float Bb, int cat,
    float& a0, float& a1, float& a2, float& a3, float& a4)
{
    const int catr    = __builtin_amdgcn_readlane(cat, rr);
    const float rev0  = bcastf(th2min_rev, rr);
    const float stp_r = bcastf(stp_rev, rr);
    const float ca5_r = bcastf(ca5, rr);
    const float sa5_r = bcastf(sa5, rr);
    const float P_r   = bcastf(P, rr);
    const float Q_r   = bcastf(Q, rr);
    const float R_r   = bcastf(R, rr);
    const float S_r   = bcastf(S, rr);
    const float Bb_r  = bcastf(Bb, rr);

    const float rev = fmaf(stp_r, flane, rev0);
    float sth, cth;
    hw_sincos_rev(rev, &sth, &cth);
    const float a  = fmaf(-Q_r, cth, P_r);
    const float cc = fmaf(-S_r, cth, R_r);
    const float b  = Bb_r * sth;
    const float disc = fmaf(b, b, -4.0f * (a * cc));
    const bool bad = disc < 0.0f;
    const float D = __builtin_amdgcn_sqrtf(fmaxf(disc, 0.0f));
    const float w = D - b;
    const float s = a + a;
    const float s2 = s * s, w2 = w * w;
    const float rden = __builtin_amdgcn_rcpf(s2 + w2);
    const float c3 = (s2 - w2) * rden;
    const float sw = s * w;
    const float s3 = (sw + sw) * rden;
    float px = fmaf(ca5_r, c3, fmaf(-sa5_r, s3, cth));
    float py = fmaf(sa5_r, c3, fmaf(ca5_r, s3, sth));
    px = bad ? 0.0f : px;
    py = bad ? 0.0f : py;
    const float dx = px - txj, dy = py - tyj;
    float ch = fmaf(dx, dx, dy * dy);
    ch = inpos ? ch : 0.0f;
    float c0 = fmaf(txj, txj, tyj * tyj);
    c0 = inpos ? c0 : 0.0f;
    a0 += (catr == 0) ? c0 : 0.0f;
    a1 += (catr == 1) ? ch : 0.0f;
    a2 += (catr == 2) ? ch : 0.0f;
    a3 += (catr == 3) ? ch : 0.0f;
    a4 += (catr == 4) ? ch : 0.0f;
}

// Unconditional coalesced load: lanes 60..63 duplicate lane 59's element (same cache line).
__device__ __forceinline__ float2 ldt(const float* __restrict__ target,
                                      int base, int rr, int lpos) {
    return *reinterpret_cast<const float2*>(
        target + (size_t)(base + rr) * (size_t)(2 * NPOS) + 2 * lpos);
}

// 8 float2 loads, all named scalars (NO arrays -> stays in VGPRs)
#define LOADB(Pfx, r0)                                                                 \
    do {                                                                               \
        float2 _v;                                                                     \
        _v = ldt(target, base, (r0) + 0, lpos); Pfx##x0 = _v.x; Pfx##y0 = _v.y;        \
        _v = ldt(target, base, (r0) + 1, lpos); Pfx##x1 = _v.x; Pfx##y1 = _v.y;        \
        _v = ldt(target, base, (r0) + 2, lpos); Pfx##x2 = _v.x; Pfx##y2 = _v.y;        \
        _v = ldt(target, base, (r0) + 3, lpos); Pfx##x3 = _v.x; Pfx##y3 = _v.y;        \
        _v = ldt(target, base, (r0) + 4, lpos); Pfx##x4 = _v.x; Pfx##y4 = _v.y;        \
        _v = ldt(target, base, (r0) + 5, lpos); Pfx##x5 = _v.x; Pfx##y5 = _v.y;        \
        _v = ldt(target, base, (r0) + 6, lpos); Pfx##x6 = _v.x; Pfx##y6 = _v.y;        \
        _v = ldt(target, base, (r0) + 7, lpos); Pfx##x7 = _v.x; Pfx##y7 = _v.y;        \
    } while (0)

#define ROWA(Pfx, rr, sx, sy)                                                          \
    row_acc((rr), Pfx##sx, Pfx##sy, flane, inpos, th2min_rev, stp_rev, ca5, sa5,       \
            Pc, Qc, Rc, Sc, Bb, cat, a0, a1, a2, a3, a4)

#define COMPUTEB(Pfx, r0)                                                              \
    do {                                                                               \
        ROWA(Pfx, (r0) + 0, x0, y0);                                                   \
        ROWA(Pfx, (r0) + 1, x1, y1);                                                   \
        ROWA(Pfx, (r0) + 2, x2, y2);                                                   \
        ROWA(Pfx, (r0) + 3, x3, y3);                                                   \
        ROWA(Pfx, (r0) + 4, x4, y4);                                                   \
        ROWA(Pfx, (r0) + 5, x5, y5);                                                   \
        ROWA(Pfx, (r0) + 6, x6, y6);                                                   \
        ROWA(Pfx, (r0) + 7, x7, y7);                                                   \
    } while (0)

__global__ __launch_bounds__(256, 6) void posloss_main(
    const float* __restrict__ pred, const float* __restrict__ target,
    float* __restrict__ out, int B, int nchunks)
{
    const int tid  = threadIdx.x;
    const int lane = tid & 63;
    const int wv   = tid >> 6;
    const int wid  = (blockIdx.x * blockDim.x + tid) >> 6;
    const bool inpos = lane < NPOS;
    const int lpos = inpos ? lane : (NPOS - 1);
    const float flane = (float)lane;

    float a0 = 0.f, a1 = 0.f, a2 = 0.f, a3 = 0.f, a4 = 0.f;

    if (wid < nchunks) {
        const int base = wid * CHUNK;
        const int rmax = (B - base) < CHUNK ? (B - base) : CHUNK;

        // ---- pred loads (lanes 0..31 own rows, 32..63 duplicate) ----
        const int prow = base + (lane & 31);
        float r1 = 2.f, r3 = 2.f, r4 = 2.f, r5 = 1.f, al = 0.f;
        if (prow < B) {
            const float* pp = pred + (size_t)prow * 5;
            r1 = pp[0]; r3 = pp[1]; r4 = pp[2]; r5 = pp[3]; al = pp[4];
        }

        // ---- prologue (libm-free) ----
        const float sumL = ((r1 + 1.0f) + r3) + r4;
        const float maxL = fmaxf(fmaxf(r1, 1.0f), fmaxf(r3, r4));
        const bool valid = (2.0f * maxL) < sumL;
        const bool c1 = ((r1 + 1.0f) - (r3 + r4)) > 0.0f;
        const bool c2 = (fabsf(r1 - 1.0f) - fabsf(r3 - r4)) >= 0.0f;
        const bool up = valid && c1 && c2;
        const bool lo = valid && (!c1) && (!c2);
        const bool bo = valid && c1 && (!c2);
        const float rdenom = __builtin_amdgcn_rcpf(2.0f * r1);
        const float s34 = r3 + r4, d34 = r3 - r4;
        const float r1sq1 = fmaf(r1, r1, 1.0f);
        float argS = (r1sq1 - s34 * s34) * rdenom;
        float argD = (r1sq1 - d34 * d34) * rdenom;
        argS = (up || bo) ? argS : 0.0f;
        argD = (lo || bo) ? argD : 0.0f;
        argS = fminf(1.0f, fmaxf(-1.0f, argS));
        argD = fminf(1.0f, fmaxf(-1.0f, argD));
        const float acS = acos_poly(argS);
        const float acD = acos_poly(argD);
        float th2min = up ? (-acS) : ((lo || bo) ? acD : 0.0f);
        float th2max = (up || bo) ? acS : (lo ? (TWO_PI_F - acD) : TWO_PI_F);
        if (!valid) { th2min = 0.0f; th2max = TWO_PI_F; }
        const float stp_rev    = (th2max - th2min) * (INV_TWO_PI_F / 59.0f);
        const float th2min_rev = th2min * INV_TWO_PI_F;
        const int cat = (!valid) ? 0 : (up ? 1 : (lo ? 2 : (bo ? 3 : 4)));
        float sal, cal;
        hw_sincos_rev(al * INV_TWO_PI_F, &sal, &cal);
        const float ca5 = r5 * cal, sa5 = r5 * sal;
        const float K1c = fmaf(r3, r3, r1sq1) - r4 * r4;
        const float K1m = 2.0f * r1;
        const float A2  = (2.0f * r1) * r3;
        const float B2  = 2.0f * r3;
        const float Pc = K1c + A2;
        const float Qc = K1m + B2;
        const float Rc = K1c - A2;
        const float Sc = K1m - B2;
        const float Bb = 2.0f * B2;

        if (rmax == CHUNK) {
            // ---- 2x8-row bursts in named scalars; 8-16 loads in flight ----
            float Ax0,Ay0,Ax1,Ay1,Ax2,Ay2,Ax3,Ay3,Ax4,Ay4,Ax5,Ay5,Ax6,Ay6,Ax7,Ay7;
            float Bx0,By0,Bx1,By1,Bx2,By2,Bx3,By3,Bx4,By4,Bx5,By5,Bx6,By6,Bx7,By7;
            LOADB(A, 0);
            LOADB(B, 8);
            COMPUTEB(A, 0);
            LOADB(A, 16);
            COMPUTEB(B, 8);
            LOADB(B, 24);
            COMPUTEB(A, 16);
            COMPUTEB(B, 24);
        } else {
            for (int rr = 0; rr < rmax; ++rr) {
                const float2 tv = ldt(target, base, rr, lpos);
                row_acc(rr, tv.x, tv.y, flane, inpos, th2min_rev, stp_rev, ca5, sa5,
                        Pc, Qc, Rc, Sc, Bb, cat, a0, a1, a2, a3, a4);
            }
        }
    }

    // ---- wave reduce (64 lanes) ----
    for (int off = 32; off; off >>= 1) {
        a0 += __shfl_xor(a0, off);
        a1 += __shfl_xor(a1, off);
        a2 += __shfl_xor(a2, off);
        a3 += __shfl_xor(a3, off);
        a4 += __shfl_xor(a4, off);
    }
    __shared__ float red[4][5];
    if (lane == 0) {
        red[wv][0] = a0; red[wv][1] = a1; red[wv][2] = a2; red[wv][3] = a3; red[wv][4] = a4;
    }
    __syncthreads();
    if (tid < 5) {
        const float s = ((red[0][tid] + red[1][tid]) + red[2][tid]) + red[3][tid];
        const float invB = 1.0f / (float)B;   // B = 2^18: exact
        atomicAdd(&out[tid], s * invB);
    }
}

extern "C" void kernel_launch(void* const* d_in, const int* in_sizes, int n_in,
                              void* d_out, int out_size, void* d_ws, size_t ws_size,
                              hipStream_t stream) {
    (void)n_in; (void)out_size; (void)d_ws; (void)ws_size;
    const float* pred   = (const float*)d_in[0];
    const float* target = (const float*)d_in[1];
    float* out = (float*)d_out;
    const int B = in_sizes[0] / 5;
    const int nchunks = (B + CHUNK - 1) / CHUNK;
    const int nblocks = (nchunks + 3) / 4;   // 4 waves per block, 1 chunk per wave
    hipMemsetAsync(out, 0, 5 * sizeof(float), stream);
    posloss_main<<<nblocks, 256, 0, stream>>>(pred, target, out, B, nchunks);
}

// Round 12
// 39.489 us; speedup vs baseline: 1.2078x; 1.2078x over previous
//
#include <hip/hip_runtime.h>
#include <math.h>

#define CHUNK 32
#define NPOS 60
#define TWO_PI_F 6.283185307179586f
#define INV_TWO_PI_F 0.15915494309189535f
#define PI_F 3.14159265358979f

__device__ __forceinline__ float bcastf(float v, int l) {
    return __builtin_bit_cast(float, __builtin_amdgcn_readlane(__builtin_bit_cast(int, v), l));
}

// acos via Abramowitz-Stegun 4-term: max abs err ~6.7e-5 rad
__device__ __forceinline__ float acos_poly(float x) {
    const float ax = fabsf(x);
    const float s = __builtin_amdgcn_sqrtf(fmaxf(0.0f, 1.0f - ax));
    float p = fmaf(ax, -0.0187293f, 0.0742610f);
    p = fmaf(ax, p, -0.2121144f);
    p = fmaf(ax, p, 1.5707288f);
    const float r = s * p;
    return (x < 0.0f) ? (PI_F - r) : r;
}

__device__ __forceinline__ void hw_sincos_rev(float rev, float* s, float* c) {
    const float f = __builtin_amdgcn_fractf(rev);
    *s = __builtin_amdgcn_sinf(f);
    *c = __builtin_amdgcn_cosf(f);
}

// One row's contribution. FULLY BRANCHLESS (branches in the unrolled body
// collapse the burst pipeline -- R7/R9). Per-row consts via readlane (SGPR).
__device__ __forceinline__ void row_acc(
    int rr, float txj, float tyj, float flane, bool inpos,
    float th2min_rev, float stp_rev, float ca5, float sa5,
    float P, float Q, float R, float S, float Bb, int cat,
    float& a0, float& a1, float& a2, float& a3, float& a4)
{
    const int catr    = __builtin_amdgcn_readlane(cat, rr);
    const float rev0  = bcastf(th2min_rev, rr);
    const float stp_r = bcastf(stp_rev, rr);
    const float ca5_r = bcastf(ca5, rr);
    const float sa5_r = bcastf(sa5, rr);
    const float P_r   = bcastf(P, rr);
    const float Q_r   = bcastf(Q, rr);
    const float R_r   = bcastf(R, rr);
    const float S_r   = bcastf(S, rr);
    const float Bb_r  = bcastf(Bb, rr);

    const float rev = fmaf(stp_r, flane, rev0);
    float sth, cth;
    hw_sincos_rev(rev, &sth, &cth);
    const float a  = fmaf(-Q_r, cth, P_r);
    const float cc = fmaf(-S_r, cth, R_r);
    const float b  = Bb_r * sth;
    const float disc = fmaf(b, b, -4.0f * (a * cc));
    const bool bad = disc < 0.0f;
    const float D = __builtin_amdgcn_sqrtf(fmaxf(disc, 0.0f));
    const float w = D - b;
    const float s = a + a;
    const float s2 = s * s, w2 = w * w;
    const float rden = __builtin_amdgcn_rcpf(s2 + w2);
    const float c3 = (s2 - w2) * rden;
    const float sw = s * w;
    const float s3 = (sw + sw) * rden;
    float px = fmaf(ca5_r, c3, fmaf(-sa5_r, s3, cth));
    float py = fmaf(sa5_r, c3, fmaf(ca5_r, s3, sth));
    px = bad ? 0.0f : px;
    py = bad ? 0.0f : py;
    const float dx = px - txj, dy = py - tyj;
    float ch = fmaf(dx, dx, dy * dy);
    ch = inpos ? ch : 0.0f;
    float c0 = fmaf(txj, txj, tyj * tyj);
    c0 = inpos ? c0 : 0.0f;
    a0 += (catr == 0) ? c0 : 0.0f;
    a1 += (catr == 1) ? ch : 0.0f;
    a2 += (catr == 2) ? ch : 0.0f;
    a3 += (catr == 3) ? ch : 0.0f;
    a4 += (catr == 4) ? ch : 0.0f;
}

// Unconditional coalesced load: lanes 60..63 duplicate lane 59's element (same cache line).
__device__ __forceinline__ float2 ldt(const float* __restrict__ target,
                                      int base, int rr, int lpos) {
    return *reinterpret_cast<const float2*>(
        target + (size_t)(base + rr) * (size_t)(2 * NPOS) + 2 * lpos);
}

// 8 float2 loads, all named scalars (NO arrays -> stays in VGPRs)
#define LOADB(Pfx, r0)                                                                 \
    do {                                                                               \
        float2 _v;                                                                     \
        _v = ldt(target, base, (r0) + 0, lpos); Pfx##x0 = _v.x; Pfx##y0 = _v.y;        \
        _v = ldt(target, base, (r0) + 1, lpos); Pfx##x1 = _v.x; Pfx##y1 = _v.y;        \
        _v = ldt(target, base, (r0) + 2, lpos); Pfx##x2 = _v.x; Pfx##y2 = _v.y;        \
        _v = ldt(target, base, (r0) + 3, lpos); Pfx##x3 = _v.x; Pfx##y3 = _v.y;        \
        _v = ldt(target, base, (r0) + 4, lpos); Pfx##x4 = _v.x; Pfx##y4 = _v.y;        \
        _v = ldt(target, base, (r0) + 5, lpos); Pfx##x5 = _v.x; Pfx##y5 = _v.y;        \
        _v = ldt(target, base, (r0) + 6, lpos); Pfx##x6 = _v.x; Pfx##y6 = _v.y;        \
        _v = ldt(target, base, (r0) + 7, lpos); Pfx##x7 = _v.x; Pfx##y7 = _v.y;        \
    } while (0)

#define ROWA(Pfx, rr, sx, sy)                                                          \
    row_acc((rr), Pfx##sx, Pfx##sy, flane, inpos, th2min_rev, stp_rev, ca5, sa5,       \
            Pc, Qc, Rc, Sc, Bb, cat, a0, a1, a2, a3, a4)

#define COMPUTEB(Pfx, r0)                                                              \
    do {                                                                               \
        ROWA(Pfx, (r0) + 0, x0, y0);                                                   \
        ROWA(Pfx, (r0) + 1, x1, y1);                                                   \
        ROWA(Pfx, (r0) + 2, x2, y2);                                                   \
        ROWA(Pfx, (r0) + 3, x3, y3);                                                   \
        ROWA(Pfx, (r0) + 4, x4, y4);                                                   \
        ROWA(Pfx, (r0) + 5, x5, y5);                                                   \
        ROWA(Pfx, (r0) + 6, x6, y6);                                                   \
        ROWA(Pfx, (r0) + 7, x7, y7);                                                   \
    } while (0)

__global__ __launch_bounds__(256, 4) void posloss_main(
    const float* __restrict__ pred, const float* __restrict__ target,
    float* __restrict__ partials, int B, int nchunks)
{
    const int tid  = threadIdx.x;
    const int lane = tid & 63;
    const int wv   = tid >> 6;
    const int wid  = (blockIdx.x * blockDim.x + tid) >> 6;
    const bool inpos = lane < NPOS;
    const int lpos = inpos ? lane : (NPOS - 1);
    const float flane = (float)lane;

    float a0 = 0.f, a1 = 0.f, a2 = 0.f, a3 = 0.f, a4 = 0.f;

    if (wid < nchunks) {
        const int base = wid * CHUNK;
        const int rmax = (B - base) < CHUNK ? (B - base) : CHUNK;

        // ---- pred loads first (gate the longest dependent chain) ----
        const int prow = base + (lane & 31);
        float r1 = 2.f, r3 = 2.f, r4 = 2.f, r5 = 1.f, al = 0.f;
        if (prow < B) {
            const float* pp = pred + (size_t)prow * 5;
            r1 = pp[0]; r3 = pp[1]; r4 = pp[2]; r5 = pp[3]; al = pp[4];
        }

        if (rmax == CHUNK) {
            // ---- FULL-CHUNK PREFETCH: all 32 rows (16 KB/wave) in flight ----
            // Keeps ~37 outstanding loads per wave until consumed -> memory
            // pipe stays saturated instead of going idle during compute
            // phases (the lockstep-burst stall that capped R8 at 2x BW floor).
            float Ax0,Ay0,Ax1,Ay1,Ax2,Ay2,Ax3,Ay3,Ax4,Ay4,Ax5,Ay5,Ax6,Ay6,Ax7,Ay7;
            float Bx0,By0,Bx1,By1,Bx2,By2,Bx3,By3,Bx4,By4,Bx5,By5,Bx6,By6,Bx7,By7;
            float Cx0,Cy0,Cx1,Cy1,Cx2,Cy2,Cx3,Cy3,Cx4,Cy4,Cx5,Cy5,Cx6,Cy6,Cx7,Cy7;
            float Dx0,Dy0,Dx1,Dy1,Dx2,Dy2,Dx3,Dy3,Dx4,Dy4,Dx5,Dy5,Dx6,Dy6,Dx7,Dy7;
            LOADB(A, 0);
            LOADB(B, 8);
            LOADB(C, 16);
            LOADB(D, 24);

            // ---- prologue (libm-free), overlaps the load latency ----
            const float sumL = ((r1 + 1.0f) + r3) + r4;
            const float maxL = fmaxf(fmaxf(r1, 1.0f), fmaxf(r3, r4));
            const bool valid = (2.0f * maxL) < sumL;
            const bool c1 = ((r1 + 1.0f) - (r3 + r4)) > 0.0f;
            const bool c2 = (fabsf(r1 - 1.0f) - fabsf(r3 - r4)) >= 0.0f;
            const bool up = valid && c1 && c2;
            const bool lo = valid && (!c1) && (!c2);
            const bool bo = valid && c1 && (!c2);
            const float rdenom = __builtin_amdgcn_rcpf(2.0f * r1);
            const float s34 = r3 + r4, d34 = r3 - r4;
            const float r1sq1 = fmaf(r1, r1, 1.0f);
            float argS = (r1sq1 - s34 * s34) * rdenom;
            float argD = (r1sq1 - d34 * d34) * rdenom;
            argS = (up || bo) ? argS : 0.0f;
            argD = (lo || bo) ? argD : 0.0f;
            argS = fminf(1.0f, fmaxf(-1.0f, argS));
            argD = fminf(1.0f, fmaxf(-1.0f, argD));
            const float acS = acos_poly(argS);
            const float acD = acos_poly(argD);
            float th2min = up ? (-acS) : ((lo || bo) ? acD : 0.0f);
            float th2max = (up || bo) ? acS : (lo ? (TWO_PI_F - acD) : TWO_PI_F);
            if (!valid) { th2min = 0.0f; th2max = TWO_PI_F; }
            const float stp_rev    = (th2max - th2min) * (INV_TWO_PI_F / 59.0f);
            const float th2min_rev = th2min * INV_TWO_PI_F;
            const int cat = (!valid) ? 0 : (up ? 1 : (lo ? 2 : (bo ? 3 : 4)));
            float sal, cal;
            hw_sincos_rev(al * INV_TWO_PI_F, &sal, &cal);
            const float ca5 = r5 * cal, sa5 = r5 * sal;
            const float K1c = fmaf(r3, r3, r1sq1) - r4 * r4;
            const float K1m = 2.0f * r1;
            const float A2  = (2.0f * r1) * r3;
            const float B2  = 2.0f * r3;
            const float Pc = K1c + A2;
            const float Qc = K1m + B2;
            const float Rc = K1c - A2;
            const float Sc = K1m - B2;
            const float Bb = 2.0f * B2;

            COMPUTEB(A, 0);
            COMPUTEB(B, 8);
            COMPUTEB(C, 16);
            COMPUTEB(D, 24);
        } else {
            // rare partial-chunk fallback (never taken for B = 2^18)
            const float sumL = ((r1 + 1.0f) + r3) + r4;
            const float maxL = fmaxf(fmaxf(r1, 1.0f), fmaxf(r3, r4));
            const bool valid = (2.0f * maxL) < sumL;
            const bool c1 = ((r1 + 1.0f) - (r3 + r4)) > 0.0f;
            const bool c2 = (fabsf(r1 - 1.0f) - fabsf(r3 - r4)) >= 0.0f;
            const bool up = valid && c1 && c2;
            const bool lo = valid && (!c1) && (!c2);
            const bool bo = valid && c1 && (!c2);
            const float rdenom = __builtin_amdgcn_rcpf(2.0f * r1);
            const float s34 = r3 + r4, d34 = r3 - r4;
            const float r1sq1 = fmaf(r1, r1, 1.0f);
            float argS = (r1sq1 - s34 * s34) * rdenom;
            float argD = (r1sq1 - d34 * d34) * rdenom;
            argS = (up || bo) ? argS : 0.0f;
            argD = (lo || bo) ? argD : 0.0f;
            argS = fminf(1.0f, fmaxf(-1.0f, argS));
            argD = fminf(1.0f, fmaxf(-1.0f, argD));
            const float acS = acos_poly(argS);
            const float acD = acos_poly(argD);
            float th2min = up ? (-acS) : ((lo || bo) ? acD : 0.0f);
            float th2max = (up || bo) ? acS : (lo ? (TWO_PI_F - acD) : TWO_PI_F);
            if (!valid) { th2min = 0.0f; th2max = TWO_PI_F; }
            const float stp_rev    = (th2max - th2min) * (INV_TWO_PI_F / 59.0f);
            const float th2min_rev = th2min * INV_TWO_PI_F;
            const int cat = (!valid) ? 0 : (up ? 1 : (lo ? 2 : (bo ? 3 : 4)));
            float sal, cal;
            hw_sincos_rev(al * INV_TWO_PI_F, &sal, &cal);
            const float ca5 = r5 * cal, sa5 = r5 * sal;
            const float K1c = fmaf(r3, r3, r1sq1) - r4 * r4;
            const float K1m = 2.0f * r1;
            const float A2  = (2.0f * r1) * r3;
            const float B2  = 2.0f * r3;
            const float Pc = K1c + A2;
            const float Qc = K1m + B2;
            const float Rc = K1c - A2;
            const float Sc = K1m - B2;
            const float Bb = 2.0f * B2;

            for (int rr = 0; rr < rmax; ++rr) {
                const float2 tv = ldt(target, base, rr, lpos);
                row_acc(rr, tv.x, tv.y, flane, inpos, th2min_rev, stp_rev, ca5, sa5,
                        Pc, Qc, Rc, Sc, Bb, cat, a0, a1, a2, a3, a4);
            }
        }
    }

    // ---- wave reduce (64 lanes) ----
    for (int off = 32; off; off >>= 1) {
        a0 += __shfl_xor(a0, off);
        a1 += __shfl_xor(a1, off);
        a2 += __shfl_xor(a2, off);
        a3 += __shfl_xor(a3, off);
        a4 += __shfl_xor(a4, off);
    }
    __shared__ float red[4][5];
    if (lane == 0) {
        red[wv][0] = a0; red[wv][1] = a1; red[wv][2] = a2; red[wv][3] = a3; red[wv][4] = a4;
    }
    __syncthreads();
    if (tid < 5) {
        const float s = ((red[0][tid] + red[1][tid]) + red[2][tid]) + red[3][tid];
        partials[(size_t)tid * gridDim.x + blockIdx.x] = s;
    }
}

__global__ void posloss_reduce(const float* __restrict__ partials, float* __restrict__ out,
                               int nblocks, int B)
{
    const int w = threadIdx.x >> 6, lane = threadIdx.x & 63;
    if (w >= 5) return;
    double s0 = 0.0, s1 = 0.0, s2 = 0.0, s3 = 0.0;
    const float* p = partials + (size_t)w * nblocks;
    for (int k = lane; k + 192 < nblocks; k += 256) {
        s0 += (double)p[k];
        s1 += (double)p[k + 64];
        s2 += (double)p[k + 128];
        s3 += (double)p[k + 192];
    }
    double s = (s0 + s1) + (s2 + s3);
    for (int off = 32; off; off >>= 1) s += __shfl_down(s, off);
    if (lane == 0) out[w] = (float)(s / (double)B);
}

extern "C" void kernel_launch(void* const* d_in, const int* in_sizes, int n_in,
                              void* d_out, int out_size, void* d_ws, size_t ws_size,
                              hipStream_t stream) {
    (void)n_in; (void)out_size; (void)ws_size;
    const float* pred   = (const float*)d_in[0];
    const float* target = (const float*)d_in[1];
    float* out = (float*)d_out;
    float* partials = (float*)d_ws;
    const int B = in_sizes[0] / 5;
    const int nchunks = (B + CHUNK - 1) / CHUNK;
    const int nblocks = 2048;
    posloss_main<<<nblocks, 256, 0, stream>>>(pred, target, partials, B, nchunks);
    posloss_reduce<<<1, 320, 0, stream>>>(partials, out, nblocks, B);
}